// Round 9
// baseline (389.238 us; speedup 1.0000x reference)
//
#include <hip/hip_runtime.h>
#include <hip/hip_bf16.h>

#define BB 16
#define NN 4096
#define NPOINTS 1024
#define KK 32
#define NPTS (BB*NPOINTS)        // 16384
#define NWN  (BB*NPOINTS*KK)     // 524288
#define EPSF 1e-5f

typedef unsigned short u16;
typedef u16  u16x8 __attribute__((ext_vector_type(8)));
typedef short s16x8 __attribute__((ext_vector_type(8)));
typedef float f32x4 __attribute__((ext_vector_type(4)));
typedef float f32x4u __attribute__((ext_vector_type(4), aligned(4)));

__device__ __forceinline__ float bf(u16 u){
  union { unsigned int i; float f; } v; v.i = ((unsigned int)u) << 16; return v.f;
}
// native bf16 convert: compiler emits v_cvt_pk_bf16_f32 for adjacent pairs
__device__ __forceinline__ u16 f2b(float f){
  __hip_bfloat16 h = __float2bfloat16(f);
  union { __hip_bfloat16 hh; u16 u; } v; v.hh = h; return v.u;
}

// ---------------- k_init: new_xyz gather (blocks 0..63) + lw transpose (blocks 64..127) ----------------
__global__ __launch_bounds__(256) void k_init(const float* xyz, const int* didx, float* out,
                                              const float* lw, u16* lwbt){
  int t = threadIdx.x;
  if (blockIdx.x < 64){
    int p = blockIdx.x * 256 + t;
    int b = p >> 10;
    int idx = didx[p];
    const float* src = xyz + ((size_t)(b * NN + idx)) * 3;
    float* dst = out + (size_t)p * 3;
    dst[0] = src[0]; dst[1] = src[1]; dst[2] = src[2];
  } else {
    __shared__ float T[64][65];
    int kb = (blockIdx.x - 64) * 64;
    {
      int k = t >> 2, c4 = t & 3;
      #pragma unroll
      for (int j = 0; j < 4; ++j)
        *(f32x4*)&T[k][c4*16 + j*4] = *(const f32x4*)(lw + (size_t)(kb + k)*64 + c4*16 + j*4);
    }
    __syncthreads();
    {
      int n = t >> 2, k4 = t & 3;
      u16x8 o0, o1;
      #pragma unroll
      for (int j = 0; j < 8; ++j) o0[j] = f2b(T[k4*16 + j][n]);
      #pragma unroll
      for (int j = 0; j < 8; ++j) o1[j] = f2b(T[k4*16 + 8 + j][n]);
      *(u16x8*)(lwbt + (size_t)n*4096 + kb + k4*16)     = o0;
      *(u16x8*)(lwbt + (size_t)n*4096 + kb + k4*16 + 8) = o1;
    }
  }
}

// ---------------- k_stat0: raw-lc moments (3-dim Gram) ----------------
__global__ __launch_bounds__(256) void k_stat0(const float* lc, float* PA){
  int t = threadIdx.x;
  float a[9];
  #pragma unroll
  for (int r = 0; r < 9; ++r) a[r] = 0.f;
  size_t base = (size_t)blockIdx.x * 1024 + t;
  for (int ip = 0; ip < 4; ++ip){
    size_t p = base + (size_t)ip * 256;
    float x0 = lc[p*3], x1 = lc[p*3+1], x2 = lc[p*3+2];
    a[0]+=x0; a[1]+=x1; a[2]+=x2;
    a[3]+=x0*x0; a[4]+=x0*x1; a[5]+=x0*x2;
    a[6]+=x1*x1; a[7]+=x1*x2; a[8]+=x2*x2;
  }
  #pragma unroll
  for (int m = 1; m < 64; m <<= 1){
    #pragma unroll
    for (int r = 0; r < 9; ++r) a[r] += __shfl_xor(a[r], m);
  }
  if ((t & 63) == 0){
    float* dst = PA + (size_t)(blockIdx.x*4 + (t>>6)) * 16;
    f32x4 v0 = {a[0],a[1],a[2],a[3]}, v1 = {a[4],a[5],a[6],a[7]}, v2 = {a[8],0.f,0.f,0.f};
    *(f32x4*)dst = v0; *(f32x4*)(dst+4) = v1; *(f32x4*)(dst+8) = v2;
  }
}

// ---------------- k_red0 ----------------
__global__ __launch_bounds__(256) void k_red0(const float* PA, const float* w0, const float* b0,
                                              const float* g0, const float* be0, float* AD){
  __shared__ float ms[12];
  int t = threadIdx.x;
  if (t < 12){
    float s0=0,s1=0,s2=0,s3=0;
    const float* p = PA + t;
    for (int r = 0; r < 2048; r += 4){
      s0 += p[(size_t)(r+0)*16]; s1 += p[(size_t)(r+1)*16];
      s2 += p[(size_t)(r+2)*16]; s3 += p[(size_t)(r+3)*16];
    }
    ms[t] = (s0+s1)+(s2+s3);
  }
  __syncthreads();
  if (t < 16){
    float wx = w0[t*3], wy = w0[t*3+1], wz = w0[t*3+2], bb = b0[t];
    float lin = wx*ms[0] + wy*ms[1] + wz*ms[2];
    float quad = wx*wx*ms[3] + wy*wy*ms[6] + wz*wz*ms[8]
               + 2.f*(wx*wy*ms[4] + wx*wz*ms[5] + wy*wz*ms[7]);
    float S = lin + (float)NWN * bb;
    float Q = quad + 2.f*bb*lin + (float)NWN*bb*bb;
    float m = S * (1.f/NWN);
    float v = Q * (1.f/NWN) - m*m;
    float a = g0[t] * rsqrtf(v + EPSF);
    AD[t] = a; AD[16+t] = be0[t] - m*a;
  }
}

// ---------------- stat1 body (templated half) ----------------
template<int LO, int HI, bool SUMS>
__device__ __forceinline__ void stat1_body(int bid, int t, const float* lc,
                                           const f32x4* w0p, const float* a0s, const float* d0s,
                                           float* PB){
  float G[HI-LO];
  #pragma unroll
  for (int r = 0; r < HI-LO; ++r) G[r] = 0.f;
  float sh[SUMS ? 16 : 1];
  #pragma unroll
  for (int r = 0; r < (SUMS?16:1); ++r) sh[r] = 0.f;
  size_t base = (size_t)bid * 1024 + t;
  for (int ip = 0; ip < 4; ++ip){
    size_t p = base + (size_t)ip * 256;
    float x0 = lc[p*3], x1 = lc[p*3+1], x2 = lc[p*3+2];
    float h[16];
    #pragma unroll
    for (int oc = 0; oc < 16; ++oc){
      f32x4 w = w0p[oc];
      float y = w.x*x0 + w.y*x1 + w.z*x2 + w.w;
      h[oc] = fmaxf(0.f, a0s[oc]*y + d0s[oc]);
      if (SUMS) sh[oc] += h[oc];
    }
    int idx = 0;
    #pragma unroll
    for (int i = 0; i < 16; ++i){
      #pragma unroll
      for (int j = i; j < 16; ++j){
        if (idx >= LO && idx < HI) G[idx-LO] += h[i]*h[j];
        ++idx;
      }
    }
  }
  #pragma unroll
  for (int m = 1; m < 64; m <<= 1){
    #pragma unroll
    for (int r = 0; r < HI-LO; ++r) G[r] += __shfl_xor(G[r], m);
    if (SUMS){
      #pragma unroll
      for (int r = 0; r < 16; ++r) sh[r] += __shfl_xor(sh[r], m);
    }
  }
  if ((t & 63) == 0){
    float* dst = PB + (size_t)(bid*4 + (t>>6)) * 160;
    #pragma unroll
    for (int r = 0; r < HI-LO; r += 4){ f32x4 v = {G[r],G[r+1],G[r+2],G[r+3]}; *(f32x4*)(dst + LO + r) = v; }
    if (SUMS){
      #pragma unroll
      for (int r = 0; r < 16; r += 4){ f32x4 v = {sh[r],sh[r+1],sh[r+2],sh[r+3]}; *(f32x4*)(dst + 136 + r) = v; }
    }
  }
}

__global__ __launch_bounds__(256) void k_stat1(const float* lc, const float* w0, const float* b0,
                                               const float* AD, float* PB){
  __shared__ f32x4 w0p[16];
  __shared__ float a0s[16], d0s[16];
  int t = threadIdx.x;
  if (t < 16){
    f32x4 wv = {w0[t*3], w0[t*3+1], w0[t*3+2], b0[t]};
    w0p[t] = wv;
    a0s[t] = AD[t]; d0s[t] = AD[16+t];
  }
  __syncthreads();
  if (blockIdx.x < 512) stat1_body<0,68,true>(blockIdx.x, t, lc, w0p, a0s, d0s, PB);
  else                  stat1_body<68,136,false>(blockIdx.x - 512, t, lc, w0p, a0s, d0s, PB);
}

// ---------------- k_red1 ----------------
__global__ __launch_bounds__(256) void k_red1(const float* PB, const float* w1, const float* b1,
                                              const float* g1, const float* be1, float* AD){
  __shared__ float red[152];
  int t = threadIdx.x;
  if (t < 152){
    float s0=0,s1=0,s2=0,s3=0,s4=0,s5=0,s6=0,s7=0;
    const float* p = PB + t;
    for (int r = 0; r < 2048; r += 8){
      s0 += p[(size_t)(r+0)*160]; s1 += p[(size_t)(r+1)*160];
      s2 += p[(size_t)(r+2)*160]; s3 += p[(size_t)(r+3)*160];
      s4 += p[(size_t)(r+4)*160]; s5 += p[(size_t)(r+5)*160];
      s6 += p[(size_t)(r+6)*160]; s7 += p[(size_t)(r+7)*160];
    }
    red[t] = ((s0+s1)+(s2+s3)) + ((s4+s5)+(s6+s7));
  }
  __syncthreads();
  if (t < 16){
    float wv[16];
    #pragma unroll
    for (int ic = 0; ic < 16; ++ic) wv[ic] = w1[t*16+ic];
    float lin = 0.f;
    #pragma unroll
    for (int ic = 0; ic < 16; ++ic) lin += wv[ic]*red[136+ic];
    float quad = 0.f; int idx = 0;
    for (int i = 0; i < 16; ++i)
      for (int j = i; j < 16; ++j){
        float M = red[idx++];
        quad += wv[i]*wv[j]*M*((i==j)?1.f:2.f);
      }
    float bb = b1[t];
    float S = lin + (float)NWN * bb;
    float Q = quad + 2.f*bb*lin + (float)NWN*bb*bb;
    float m = S * (1.f/NWN);
    float v = Q * (1.f/NWN) - m*m;
    float a = g1[t] * rsqrtf(v + EPSF);
    AD[32+t] = a; AD[48+t] = be1[t] - m*a;
  }
}

// ---------------- stat2 body (templated half) ----------------
template<int LO, int HI, bool SUMS>
__device__ __forceinline__ void stat2_body(int bid, int t, const float* lc,
                                           const f32x4* w0p, const float* a0s, const float* d0s,
                                           const float* w1s, const float* b1s,
                                           const float* a1s, const float* d1s,
                                           float* PB){
  float G[HI-LO];
  #pragma unroll
  for (int r = 0; r < HI-LO; ++r) G[r] = 0.f;
  float sh[SUMS ? 16 : 1];
  #pragma unroll
  for (int r = 0; r < (SUMS?16:1); ++r) sh[r] = 0.f;
  size_t base = (size_t)bid * 1024 + t;
  for (int ip = 0; ip < 4; ++ip){
    size_t p = base + (size_t)ip * 256;
    float x0 = lc[p*3], x1 = lc[p*3+1], x2 = lc[p*3+2];
    float h0[16];
    #pragma unroll
    for (int oc = 0; oc < 16; ++oc){
      f32x4 w = w0p[oc];
      float y = w.x*x0 + w.y*x1 + w.z*x2 + w.w;
      h0[oc] = fmaxf(0.f, a0s[oc]*y + d0s[oc]);
    }
    float h[16];
    #pragma unroll
    for (int oc = 0; oc < 16; ++oc){
      const f32x4* wr = (const f32x4*)&w1s[oc*16];
      f32x4 wa = wr[0], wb = wr[1], wc = wr[2], wd = wr[3];
      float y = b1s[oc];
      y += wa.x*h0[0]  + wa.y*h0[1]  + wa.z*h0[2]  + wa.w*h0[3];
      y += wb.x*h0[4]  + wb.y*h0[5]  + wb.z*h0[6]  + wb.w*h0[7];
      y += wc.x*h0[8]  + wc.y*h0[9]  + wc.z*h0[10] + wc.w*h0[11];
      y += wd.x*h0[12] + wd.y*h0[13] + wd.z*h0[14] + wd.w*h0[15];
      h[oc] = fmaxf(0.f, a1s[oc]*y + d1s[oc]);
      if (SUMS) sh[oc] += h[oc];
    }
    int idx = 0;
    #pragma unroll
    for (int i = 0; i < 16; ++i){
      #pragma unroll
      for (int j = i; j < 16; ++j){
        if (idx >= LO && idx < HI) G[idx-LO] += h[i]*h[j];
        ++idx;
      }
    }
  }
  #pragma unroll
  for (int m = 1; m < 64; m <<= 1){
    #pragma unroll
    for (int r = 0; r < HI-LO; ++r) G[r] += __shfl_xor(G[r], m);
    if (SUMS){
      #pragma unroll
      for (int r = 0; r < 16; ++r) sh[r] += __shfl_xor(sh[r], m);
    }
  }
  if ((t & 63) == 0){
    float* dst = PB + (size_t)(bid*4 + (t>>6)) * 160;
    #pragma unroll
    for (int r = 0; r < HI-LO; r += 4){ f32x4 v = {G[r],G[r+1],G[r+2],G[r+3]}; *(f32x4*)(dst + LO + r) = v; }
    if (SUMS){
      #pragma unroll
      for (int r = 0; r < 16; r += 4){ f32x4 v = {sh[r],sh[r+1],sh[r+2],sh[r+3]}; *(f32x4*)(dst + 136 + r) = v; }
    }
  }
}

__global__ __launch_bounds__(256) void k_stat2(const float* lc, const float* w0, const float* b0,
                                               const float* w1, const float* b1,
                                               const float* AD, float* PB){
  __shared__ f32x4 w0p[16];
  __shared__ float a0s[16], d0s[16];
  __shared__ float w1s[256];
  __shared__ float b1s[16], a1s[16], d1s[16];
  int t = threadIdx.x;
  if (t < 16){
    f32x4 wv = {w0[t*3], w0[t*3+1], w0[t*3+2], b0[t]};
    w0p[t] = wv;
    a0s[t] = AD[t]; d0s[t] = AD[16+t];
    b1s[t] = b1[t]; a1s[t] = AD[32+t]; d1s[t] = AD[48+t];
  }
  w1s[t] = w1[t];
  __syncthreads();
  if (blockIdx.x < 512) stat2_body<0,68,true>(blockIdx.x, t, lc, w0p, a0s, d0s, w1s, b1s, a1s, d1s, PB);
  else                  stat2_body<68,136,false>(blockIdx.x - 512, t, lc, w0p, a0s, d0s, w1s, b1s, a1s, d1s, PB);
}

// ---------------- k_red2 ----------------
__global__ __launch_bounds__(256) void k_red2(const float* PB, const float* w2, const float* b2,
                                              const float* g2, const float* be2, float* AD){
  __shared__ float red[152];
  int t = threadIdx.x;
  if (t < 152){
    float s0=0,s1=0,s2=0,s3=0,s4=0,s5=0,s6=0,s7=0;
    const float* p = PB + t;
    for (int r = 0; r < 2048; r += 8){
      s0 += p[(size_t)(r+0)*160]; s1 += p[(size_t)(r+1)*160];
      s2 += p[(size_t)(r+2)*160]; s3 += p[(size_t)(r+3)*160];
      s4 += p[(size_t)(r+4)*160]; s5 += p[(size_t)(r+5)*160];
      s6 += p[(size_t)(r+6)*160]; s7 += p[(size_t)(r+7)*160];
    }
    red[t] = ((s0+s1)+(s2+s3)) + ((s4+s5)+(s6+s7));
  }
  __syncthreads();
  if (t < 64){
    float wv[16];
    #pragma unroll
    for (int ic = 0; ic < 16; ++ic) wv[ic] = w2[t*16+ic];
    float lin = 0.f;
    #pragma unroll
    for (int ic = 0; ic < 16; ++ic) lin += wv[ic]*red[136+ic];
    float quad = 0.f; int idx = 0;
    for (int i = 0; i < 16; ++i)
      for (int j = i; j < 16; ++j){
        float M = red[idx++];
        quad += wv[i]*wv[j]*M*((i==j)?1.f:2.f);
      }
    float bb = b2[t];
    float S = lin + (float)NWN * bb;
    float Q = quad + 2.f*bb*lin + (float)NWN*bb*bb;
    float m = S * (1.f/NWN);
    float v = Q * (1.f/NWN) - m*m;
    float a = g2[t] * rsqrtf(v + EPSF);
    AD[64+t] = a; AD[128+t] = be2[t] - m*a;
  }
}

// ---------------- K5: one point per block — gather + WeightNet + MFMA ----------------
__global__ __launch_bounds__(256) void k_main(const float* lcg, const int* nbrg,
    const float* points, const float* xyz,
    const float* w0, const float* b0, const float* w1, const float* b1,
    const float* w2, const float* b2, const float* AD,
    u16* npw){
  __shared__ u16   Gr[32*72];
  __shared__ u16   Wr[32*72];
  __shared__ float H0s[32][17];
  __shared__ float H1s[32][20];
  __shared__ float lcs[32][4];
  __shared__ int   nbr[32];
  __shared__ float w0c[48], b0c[16], a0c[16], d0c[16];
  __shared__ float w1c[16][17], b1c[16], a1c[16], d1c[16];
  __shared__ float w2c[64][17], b2c[64], a2c[64], d2c[64];
  int t = threadIdx.x;
  int point = blockIdx.x;
  int bb = point >> 10;
  if (t < 48) w0c[t] = w0[t];
  if (t < 16){
    b0c[t] = b0[t]; b1c[t] = b1[t];
    a0c[t] = AD[t];    d0c[t] = AD[16+t];
    a1c[t] = AD[32+t]; d1c[t] = AD[48+t];
  }
  w1c[t>>4][t&15] = w1[t];
  for (int i = t; i < 1024; i += 256) w2c[i>>4][i&15] = w2[i];
  if (t < 64){
    b2c[t] = b2[t];
    a2c[t] = AD[64+t]; d2c[t] = AD[128+t];
  }
  if (t < 32) nbr[t] = nbrg[(size_t)point * 32 + t];
  if (t < 96){ int k = t / 3, c = t % 3; lcs[k][c] = lcg[(size_t)point * 96 + t]; }
  __syncthreads();   // (A)

  // gather grouped -> Gr bf16 (vectorized where possible)
  {
    int k = t >> 3, c8 = t & 7;
    int n = nbr[k];
    const float* prow = points + (size_t)(bb * NN + n) * 61;
    u16x8 g;
    if (c8 < 7){
      f32x4 lo = *(const f32x4u*)(prow + c8*8);
      f32x4 hi = *(const f32x4u*)(prow + c8*8 + 4);
      g[0]=f2b(lo.x); g[1]=f2b(lo.y); g[2]=f2b(lo.z); g[3]=f2b(lo.w);
      g[4]=f2b(hi.x); g[5]=f2b(hi.y); g[6]=f2b(hi.z); g[7]=f2b(hi.w);
    } else {
      const float* xr = xyz + (size_t)(bb * NN + n) * 3;
      f32x4 lo = *(const f32x4u*)(prow + 56);
      g[0]=f2b(lo.x); g[1]=f2b(lo.y); g[2]=f2b(lo.z); g[3]=f2b(lo.w);
      g[4]=f2b(prow[60]);
      g[5]=f2b(xr[0]); g[6]=f2b(xr[1]); g[7]=f2b(xr[2]);
    }
    *(u16x8*)&Gr[k*72 + c8*8] = g;
  }
  // H0
  #pragma unroll
  for (int jj = 0; jj < 2; ++jj){
    int l2 = t + jj * 256; int k = l2 >> 4, oc = l2 & 15;
    float y = w0c[oc*3]*lcs[k][0] + w0c[oc*3+1]*lcs[k][1] + w0c[oc*3+2]*lcs[k][2] + b0c[oc];
    H0s[k][oc] = fmaxf(0.f, a0c[oc]*y + d0c[oc]);
  }
  __syncthreads();   // (B)
  // H1
  #pragma unroll
  for (int jj = 0; jj < 2; ++jj){
    int l2 = t + jj * 256; int k = l2 >> 4, oc = l2 & 15;
    float y = b1c[oc];
    #pragma unroll
    for (int ic = 0; ic < 16; ++ic) y += w1c[oc][ic] * H0s[k][ic];
    H1s[k][oc] = fmaxf(0.f, a1c[oc]*y + d1c[oc]);
  }
  __syncthreads();   // (C)
  // W -> Wr
  {
    int o = t & 63, kb = (t >> 6) * 8;
    float wrow[16];
    #pragma unroll
    for (int ic = 0; ic < 16; ++ic) wrow[ic] = w2c[o][ic];
    float a2 = a2c[o], d2 = d2c[o], bb2 = b2c[o];
    #pragma unroll
    for (int j = 0; j < 8; ++j){
      const f32x4* hr = (const f32x4*)&H1s[kb + j][0];
      f32x4 h0v = hr[0], h1v = hr[1], h2v = hr[2], h3v = hr[3];
      float y = bb2;
      y += wrow[0]*h0v.x + wrow[1]*h0v.y + wrow[2]*h0v.z + wrow[3]*h0v.w;
      y += wrow[4]*h1v.x + wrow[5]*h1v.y + wrow[6]*h1v.z + wrow[7]*h1v.w;
      y += wrow[8]*h2v.x + wrow[9]*h2v.y + wrow[10]*h2v.z + wrow[11]*h2v.w;
      y += wrow[12]*h3v.x + wrow[13]*h3v.y + wrow[14]*h3v.z + wrow[15]*h3v.w;
      Wr[(kb + j)*72 + o] = f2b(fmaxf(0.f, a2*y + d2));
    }
  }
  __syncthreads();   // (D)
  // MFMA + store
  {
    int w = t >> 6, l = t & 63;
    int li = l & 15, lk = (l >> 4) * 8, lr = (l >> 4) * 4;
    s16x8 bfrag;
    #pragma unroll
    for (int j = 0; j < 8; ++j) bfrag[j] = (short)Wr[(lk + j)*72 + w*16 + li];
    #pragma unroll
    for (int it = 0; it < 4; ++it){
      s16x8 afrag;
      #pragma unroll
      for (int j = 0; j < 8; ++j) afrag[j] = (short)Gr[(lk + j)*72 + it*16 + li];
      f32x4 z = {0.f, 0.f, 0.f, 0.f};
      f32x4 d = __builtin_amdgcn_mfma_f32_16x16x32_bf16(afrag, bfrag, z, 0, 0, 0);
      #pragma unroll
      for (int r = 0; r < 4; ++r)
        npw[(size_t)point*4096 + (size_t)(it*16 + lr + r)*64 + w*16 + li] = f2b(d[r]);
    }
  }
}

// ---------------- k_statC: channel stats from npw (streaming, coalesced) ----------------
__global__ __launch_bounds__(256) void k_statC(const u16* npw, float* PC){
  int t = threadIdx.x;
  float s[16], q[16];
  #pragma unroll
  for (int j = 0; j < 16; ++j){ s[j] = 0.f; q[j] = 0.f; }
  size_t rowbase = (size_t)blockIdx.x * 64;
  for (int p = 0; p < 64; ++p){
    const u16* row = npw + (rowbase + p) * 4096 + t * 16;
    u16x8 a = *(const u16x8*)row;
    u16x8 b = *(const u16x8*)(row + 8);
    #pragma unroll
    for (int j = 0; j < 8; ++j){ float v = bf(a[j]); s[j]   += v; q[j]   += v*v; }
    #pragma unroll
    for (int j = 0; j < 8; ++j){ float v = bf(b[j]); s[8+j] += v; q[8+j] += v*v; }
  }
  float* dst = PC + (size_t)blockIdx.x * 8192 + t * 16;
  #pragma unroll
  for (int j = 0; j < 16; ++j){ dst[j] = s[j]; dst[4096 + j] = q[j]; }
}

// ---------------- k_finC ----------------
__global__ __launch_bounds__(256) void k_finC(const float* PC, const float* gc, const float* bc,
                                              float* AC, float* DC){
  int ch = blockIdx.x * 256 + threadIdx.x;
  float s = 0.f, q = 0.f;
  for (int r = 0; r < 256; ++r){
    s += PC[(size_t)r * 8192 + ch];
    q += PC[(size_t)r * 8192 + 4096 + ch];
  }
  float m = s * (1.f/16384.f);
  float v = q * (1.f/16384.f) - m*m;
  float a = gc[ch] * rsqrtf(v + EPSF);
  AC[ch] = a; DC[ch] = bc[ch] - m*a;
}

// ---------------- k_linear: MFMA GEMM + fused bn+relu on A + final-BN channel partials ----------------
__global__ __launch_bounds__(256) void k_linear(const u16* npw, const float* AC, const float* DC,
                                                const u16* lwbt, const float* lb, float* yw,
                                                float* PL){
  __shared__ u16 Al[32*72];
  __shared__ u16 Bl[64*72];
  __shared__ float cps[64], cpq[64];
  int t = threadIdx.x;
  int w = t >> 6, l = t & 63;
  int rowbase = blockIdx.x * 32;
  int mt = w & 1, np2 = w >> 1;
  f32x4 acc0 = {0.f,0.f,0.f,0.f}, acc1 = acc0;
  for (int kb = 0; kb < 4096; kb += 64){
    __syncthreads();
    {
      int r = t >> 3, c8 = t & 7;
      int kk = kb + c8*8;
      u16x8 u = *(const u16x8*)(npw + (size_t)(rowbase + r)*4096 + kk);
      f32x4 alo = *(const f32x4*)(AC + kk), ahi = *(const f32x4*)(AC + kk + 4);
      f32x4 dlo = *(const f32x4*)(DC + kk), dhi = *(const f32x4*)(DC + kk + 4);
      u16x8 o;
      o[0] = f2b(fmaxf(0.f, alo.x*bf(u[0]) + dlo.x));
      o[1] = f2b(fmaxf(0.f, alo.y*bf(u[1]) + dlo.y));
      o[2] = f2b(fmaxf(0.f, alo.z*bf(u[2]) + dlo.z));
      o[3] = f2b(fmaxf(0.f, alo.w*bf(u[3]) + dlo.w));
      o[4] = f2b(fmaxf(0.f, ahi.x*bf(u[4]) + dhi.x));
      o[5] = f2b(fmaxf(0.f, ahi.y*bf(u[5]) + dhi.y));
      o[6] = f2b(fmaxf(0.f, ahi.z*bf(u[6]) + dhi.z));
      o[7] = f2b(fmaxf(0.f, ahi.w*bf(u[7]) + dhi.w));
      *(u16x8*)&Al[r*72 + c8*8] = o;
    }
    #pragma unroll
    for (int jj = 0; jj < 2; ++jj){
      int n = (t >> 3) + jj*32, c8 = t & 7;
      u16x8 u = *(const u16x8*)(lwbt + (size_t)n*4096 + kb + c8*8);
      *(u16x8*)&Bl[n*72 + c8*8] = u;
    }
    __syncthreads();
    #pragma unroll
    for (int ks = 0; ks < 2; ++ks){
      s16x8 af  = *(const s16x8*)&Al[(mt*16 + (l & 15))*72 + ks*32 + (l >> 4)*8];
      s16x8 bf0 = *(const s16x8*)&Bl[((np2*2    )*16 + (l & 15))*72 + ks*32 + (l >> 4)*8];
      s16x8 bf1 = *(const s16x8*)&Bl[((np2*2 + 1)*16 + (l & 15))*72 + ks*32 + (l >> 4)*8];
      acc0 = __builtin_amdgcn_mfma_f32_16x16x32_bf16(af, bf0, acc0, 0, 0, 0);
      acc1 = __builtin_amdgcn_mfma_f32_16x16x32_bf16(af, bf1, acc1, 0, 0, 0);
    }
  }
  int col0 = np2*32 + (l & 15), col1 = col0 + 16;
  float lb0 = lb[col0], lb1 = lb[col1];
  float s0 = 0.f, q0 = 0.f, s1 = 0.f, q1 = 0.f;
  if (t < 64){ cps[t] = 0.f; cpq[t] = 0.f; }
  __syncthreads();
  #pragma unroll
  for (int r = 0; r < 4; ++r){
    int row = rowbase + mt*16 + (l >> 4)*4 + r;
    float y0 = acc0[r] + lb0;
    float y1 = acc1[r] + lb1;
    yw[(size_t)row*64 + col0] = y0;
    yw[(size_t)row*64 + col1] = y1;
    s0 += y0; q0 += y0*y0; s1 += y1; q1 += y1*y1;
  }
  atomicAdd(&cps[col0], s0); atomicAdd(&cpq[col0], q0);
  atomicAdd(&cps[col1], s1); atomicAdd(&cpq[col1], q1);
  __syncthreads();
  if (t < 64){
    PL[blockIdx.x*128 + t]      = cps[t];
    PL[blockIdx.x*128 + 64 + t] = cpq[t];
  }
}

// ---------------- k_redF: reduce 512 blocks of PL -> SL ----------------
__global__ __launch_bounds__(128) void k_redF(const float* PL, float* SL){
  int t = threadIdx.x;
  float s = 0.f;
  for (int b = 0; b < 512; ++b) s += PL[b*128 + t];
  SL[t] = s;
}

// ---------------- k_final: bn + relu + f32x4 store ----------------
__global__ __launch_bounds__(256) void k_final(const float* yw, const float* SL,
                                               const float* gl, const float* bl, float* out){
  int e = (blockIdx.x * 256 + threadIdx.x) * 4;
  int o = e & 63;
  f32x4 y = *(const f32x4*)(yw + e);
  f32x4 r;
  #pragma unroll
  for (int j = 0; j < 4; ++j){
    float m = SL[o+j] * (1.f/16384.f);
    float v = SL[64+o+j] * (1.f/16384.f) - m*m;
    float a = gl[o+j] * rsqrtf(v + EPSF);
    float d = bl[o+j] - m*a;
    r[j] = fmaxf(0.f, a*y[j] + d);
  }
  *(f32x4*)(out + 49152 + e) = r;
}

extern "C" void kernel_launch(void* const* d_in, const int* in_sizes, int n_in,
                              void* d_out, int out_size, void* d_ws, size_t ws_size,
                              hipStream_t stream){
  (void)in_sizes; (void)n_in; (void)out_size; (void)ws_size;
  const float* xyz    = (const float*)d_in[0];
  const float* points = (const float*)d_in[1];
  const float* lc     = (const float*)d_in[2];
  const int*   nbrl   = (const int*)d_in[3];
  const int*   didx   = (const int*)d_in[4];
  const float* w0 = (const float*)d_in[5];
  const float* b0 = (const float*)d_in[6];
  const float* g0 = (const float*)d_in[7];
  const float* be0= (const float*)d_in[8];
  const float* w1 = (const float*)d_in[9];
  const float* b1 = (const float*)d_in[10];
  const float* g1 = (const float*)d_in[11];
  const float* be1= (const float*)d_in[12];
  const float* w2 = (const float*)d_in[13];
  const float* b2 = (const float*)d_in[14];
  const float* g2 = (const float*)d_in[15];
  const float* be2= (const float*)d_in[16];
  const float* gc = (const float*)d_in[17];
  const float* bc = (const float*)d_in[18];
  const float* lw = (const float*)d_in[19];
  const float* lb = (const float*)d_in[20];
  const float* gl = (const float*)d_in[21];
  const float* bl = (const float*)d_in[22];
  float* out = (float*)d_out;
  char* ws = (char*)d_ws;

  float* AD  = (float*)ws;           // 192 @0
  float* SL  = AD + 192;             // 128 @192
  float* AC  = SL + 128;             // 4096 @320
  float* DC  = AC + 4096;            // 4096 @4416
  float* PA  = DC + 4096;            // 32768 @8512
  float* PB1 = PA + 32768;           // 327680 @41280
  float* PB2 = PB1 + 327680;         // 327680 @368960
  float* PL  = PB2 + 327680;         // 65536 @696640 (end 762176 floats < 4MB)
  float* PC  = (float*)(ws + 4194304);                        // 8 MB
  u16*  npw  = (u16*)(ws + 4194304 + 8388608);                // 128 MB bf16
  float* yw  = (float*)(ws + 4194304 + 8388608 + 134217728);  // 4 MB f32
  u16*  lwbt = (u16*)(ws + 4194304 + 8388608 + 134217728 + 4194304); // 512 KB

  k_init  <<<128,   256, 0, stream>>>(xyz, didx, out, lw, lwbt);
  k_stat0 <<<512,   256, 0, stream>>>(lc, PA);
  k_red0  <<<1,     256, 0, stream>>>(PA, w0, b0, g0, be0, AD);
  k_stat1 <<<1024,  256, 0, stream>>>(lc, w0, b0, AD, PB1);
  k_red1  <<<1,     256, 0, stream>>>(PB1, w1, b1, g1, be1, AD);
  k_stat2 <<<1024,  256, 0, stream>>>(lc, w0, b0, w1, b1, AD, PB2);
  k_red2  <<<1,     256, 0, stream>>>(PB2, w2, b2, g2, be2, AD);
  k_main  <<<16384, 256, 0, stream>>>(lc, nbrl, points, xyz,
                                      w0, b0, w1, b1, w2, b2, AD, npw);
  k_statC <<<256,   256, 0, stream>>>(npw, PC);
  k_finC  <<<16,    256, 0, stream>>>(PC, gc, bc, AC, DC);
  k_linear<<<512,   256, 0, stream>>>(npw, AC, DC, lwbt, lb, yw, PL);
  k_redF  <<<1,     128, 0, stream>>>(PL, SL);
  k_final <<<1024,  256, 0, stream>>>(yw, SL, gl, bl, out);
}

// Round 11
// 282.223 us; speedup vs baseline: 1.3792x; 1.3792x over previous
//
#include <hip/hip_runtime.h>
#include <hip/hip_bf16.h>

#define BB 16
#define NN 4096
#define NPOINTS 1024
#define KK 32
#define NPTS (BB*NPOINTS)        // 16384
#define NWN  (BB*NPOINTS*KK)     // 524288
#define EPSF 1e-5f
#define SGBLK 512                // stat-Gram grid
#define SGIT  4                  // iters/block: 512*4*256 = 524288

typedef unsigned short u16;
typedef u16  u16x8 __attribute__((ext_vector_type(8)));
typedef short s16x8 __attribute__((ext_vector_type(8)));
typedef float f32x4 __attribute__((ext_vector_type(4)));
typedef float f32x4u __attribute__((ext_vector_type(4), aligned(4)));

__device__ __forceinline__ float bf(u16 u){
  union { unsigned int i; float f; } v; v.i = ((unsigned int)u) << 16; return v.f;
}
__device__ __forceinline__ u16 f2b(float f){
  __hip_bfloat16 h = __float2bfloat16(f);
  union { __hip_bfloat16 hh; u16 u; } v; v.hh = h; return v.u;
}

// F layout (folded weights): [0..47] w0f, [48..63] b0f, [64..319] w1f,
// [320..335] b1f, [336..1359] w2f, [1360..1423] b2f

// ---------------- k_init: new_xyz gather (blocks 0..63) + lw transpose (64..127) ----------------
__global__ __launch_bounds__(256) void k_init(const float* xyz, const int* didx, float* out,
                                              const float* lw, u16* lwbt){
  int t = threadIdx.x;
  if (blockIdx.x < 64){
    int p = blockIdx.x * 256 + t;
    int b = p >> 10;
    int idx = didx[p];
    const float* src = xyz + ((size_t)(b * NN + idx)) * 3;
    float* dst = out + (size_t)p * 3;
    dst[0] = src[0]; dst[1] = src[1]; dst[2] = src[2];
  } else {
    __shared__ float T[64][65];
    int kb = (blockIdx.x - 64) * 64;
    {
      int k = t >> 2, c4 = t & 3;
      #pragma unroll
      for (int j = 0; j < 4; ++j)
        *(f32x4*)&T[k][c4*16 + j*4] = *(const f32x4*)(lw + (size_t)(kb + k)*64 + c4*16 + j*4);
    }
    __syncthreads();
    {
      int n = t >> 2, k4 = t & 3;
      u16x8 o0, o1;
      #pragma unroll
      for (int j = 0; j < 8; ++j) o0[j] = f2b(T[k4*16 + j][n]);
      #pragma unroll
      for (int j = 0; j < 8; ++j) o1[j] = f2b(T[k4*16 + 8 + j][n]);
      *(u16x8*)(lwbt + (size_t)n*4096 + kb + k4*16)     = o0;
      *(u16x8*)(lwbt + (size_t)n*4096 + kb + k4*16 + 8) = o1;
    }
  }
}

// ---------------- k_stat0: raw-lc moments (3-dim Gram) ----------------
__global__ __launch_bounds__(256) void k_stat0(const float* lc, float* PA){
  int t = threadIdx.x;
  float a[9];
  #pragma unroll
  for (int r = 0; r < 9; ++r) a[r] = 0.f;
  size_t base = (size_t)blockIdx.x * 1024 + t;
  for (int ip = 0; ip < 4; ++ip){
    size_t p = base + (size_t)ip * 256;
    float x0 = lc[p*3], x1 = lc[p*3+1], x2 = lc[p*3+2];
    a[0]+=x0; a[1]+=x1; a[2]+=x2;
    a[3]+=x0*x0; a[4]+=x0*x1; a[5]+=x0*x2;
    a[6]+=x1*x1; a[7]+=x1*x2; a[8]+=x2*x2;
  }
  #pragma unroll
  for (int m = 1; m < 64; m <<= 1){
    #pragma unroll
    for (int r = 0; r < 9; ++r) a[r] += __shfl_xor(a[r], m);
  }
  if ((t & 63) == 0){
    float* dst = PA + (size_t)(blockIdx.x*4 + (t>>6)) * 16;
    f32x4 v0 = {a[0],a[1],a[2],a[3]}, v1 = {a[4],a[5],a[6],a[7]}, v2 = {a[8],0.f,0.f,0.f};
    *(f32x4*)dst = v0; *(f32x4*)(dst+4) = v1; *(f32x4*)(dst+8) = v2;
  }
}

// ---------------- k_red0: layer0 BN -> folded w0f/b0f ----------------
__global__ __launch_bounds__(256) void k_red0(const float* PA, const float* w0, const float* b0,
                                              const float* g0, const float* be0, float* F){
  __shared__ float ms[12];
  __shared__ float a0sh[16];
  int t = threadIdx.x;
  if (t < 12){
    float s0=0,s1=0,s2=0,s3=0;
    const float* p = PA + t;
    for (int r = 0; r < 2048; r += 4){
      s0 += p[(size_t)(r+0)*16]; s1 += p[(size_t)(r+1)*16];
      s2 += p[(size_t)(r+2)*16]; s3 += p[(size_t)(r+3)*16];
    }
    ms[t] = (s0+s1)+(s2+s3);
  }
  __syncthreads();
  if (t < 16){
    float wx = w0[t*3], wy = w0[t*3+1], wz = w0[t*3+2], bb = b0[t];
    float lin = wx*ms[0] + wy*ms[1] + wz*ms[2];
    float quad = wx*wx*ms[3] + wy*wy*ms[6] + wz*wz*ms[8]
               + 2.f*(wx*wy*ms[4] + wx*wz*ms[5] + wy*wz*ms[7]);
    float S = lin + (float)NWN * bb;
    float Q = quad + 2.f*bb*lin + (float)NWN*bb*bb;
    float m = S * (1.f/NWN);
    float v = Q * (1.f/NWN) - m*m;
    float a = g0[t] * rsqrtf(v + EPSF);
    float d = be0[t] - m*a;
    a0sh[t] = a;
    F[48+t] = a*bb + d;
  }
  __syncthreads();
  if (t < 48) F[t] = a0sh[t/3] * w0[t];
}

// ---------------- k_statG: MFMA-Gram stat pass (L2=false: h0; true: h1) ----------------
// FIX vs round 10: channel-major LDS tile (stride 72 u16, 16B-aligned rows) with
// __syncthreads() around the MFMA reads — the round-10 version had an unfenced
// type-punned LDS write->read that the compiler could (and did) reorder.
template<bool L2>
__global__ __launch_bounds__(256) void k_statG(const float* lc, const float* F, float* PB){
  __shared__ f32x4 w0p[16];          // xyz = w0f row, w = b0f
  __shared__ float w1s[256], b1fs[16];
  __shared__ __align__(16) u16 Ht[4][16*72];   // per-wave: [ch][pt], 16 ch x 64 pts, stride 72
  __shared__ float GS[4][16][17];
  __shared__ float SHs[4][16];
  int t = threadIdx.x;
  int w = t >> 6, l = t & 63;
  if (t < 16){
    f32x4 wv = {F[t*3], F[t*3+1], F[t*3+2], F[48+t]};
    w0p[t] = wv;
    if (L2) b1fs[t] = F[320+t];
  }
  if (L2) w1s[t] = F[64+t];
  __syncthreads();
  f32x4 acc = {0.f,0.f,0.f,0.f};
  float sh[16];
  #pragma unroll
  for (int r = 0; r < 16; ++r) sh[r] = 0.f;
  u16* Hw = &Ht[w][0];
  for (int it = 0; it < SGIT; ++it){
    size_t p = (size_t)blockIdx.x * (SGIT*256) + (size_t)it*256 + w*64 + l;
    float x0 = lc[p*3], x1 = lc[p*3+1], x2 = lc[p*3+2];
    float h[16];
    #pragma unroll
    for (int oc = 0; oc < 16; ++oc){
      f32x4 wv = w0p[oc];
      h[oc] = fmaxf(0.f, wv.x*x0 + wv.y*x1 + wv.z*x2 + wv.w);
    }
    if (L2){
      float h1[16];
      #pragma unroll
      for (int oc = 0; oc < 16; ++oc){
        const f32x4* wr = (const f32x4*)&w1s[oc*16];
        f32x4 wa = wr[0], wb = wr[1], wc = wr[2], wd = wr[3];
        float y = b1fs[oc];
        y += wa.x*h[0]  + wa.y*h[1]  + wa.z*h[2]  + wa.w*h[3];
        y += wb.x*h[4]  + wb.y*h[5]  + wb.z*h[6]  + wb.w*h[7];
        y += wc.x*h[8]  + wc.y*h[9]  + wc.z*h[10] + wc.w*h[11];
        y += wd.x*h[12] + wd.y*h[13] + wd.z*h[14] + wd.w*h[15];
        h1[oc] = fmaxf(0.f, y);
      }
      #pragma unroll
      for (int oc = 0; oc < 16; ++oc) h[oc] = h1[oc];
    }
    #pragma unroll
    for (int oc = 0; oc < 16; ++oc) sh[oc] += h[oc];
    // pack h -> channel-major wave tile: Hw[c][pt=l] (same-type u16 stores, conflict-free)
    #pragma unroll
    for (int c = 0; c < 16; ++c) Hw[c*72 + l] = f2b(h[c]);
    __syncthreads();   // writes visible + compiler-ordered before reads
    // Gram via MFMA: A-frag == B-frag (A[r][k]=h_k[r], B[k][c]=h_k[c] identical per-lane)
    #pragma unroll
    for (int tt = 0; tt < 2; ++tt){
      s16x8 af = *(const s16x8*)&Hw[(l & 15)*72 + tt*32 + (l >> 4)*8];  // aligned b128
      acc = __builtin_amdgcn_mfma_f32_16x16x32_bf16(af, af, acc, 0, 0, 0);
    }
    __syncthreads();   // reads done before next iteration overwrites
  }
  // C layout: col = l&15, row = (l>>4)*4 + r  [m89]
  #pragma unroll
  for (int r = 0; r < 4; ++r)
    GS[w][(l>>4)*4 + r][l & 15] = acc[r];
  #pragma unroll
  for (int m = 1; m < 64; m <<= 1){
    #pragma unroll
    for (int r = 0; r < 16; ++r) sh[r] += __shfl_xor(sh[r], m);
  }
  if (l == 0){
    #pragma unroll
    for (int r = 0; r < 16; ++r) SHs[w][r] = sh[r];
  }
  __syncthreads();
  {
    int i = t >> 4, j = t & 15;
    float g = GS[0][i][j] + GS[1][i][j] + GS[2][i][j] + GS[3][i][j];
    PB[(size_t)blockIdx.x*272 + t] = g;
    if (t < 16)
      PB[(size_t)blockIdx.x*272 + 256 + t] = SHs[0][t]+SHs[1][t]+SHs[2][t]+SHs[3][t];
  }
}

// ---------------- k_red1: Gram -> layer1 BN -> folded w1f/b1f ----------------
__global__ __launch_bounds__(256) void k_red1(const float* PB, const float* w1, const float* b1,
                                              const float* g1, const float* be1, float* F){
  __shared__ float red[272];
  __shared__ float a1sh[16];
  int t = threadIdx.x;
  for (int e = t; e < 272; e += 256){
    float s = 0.f;
    for (int r = 0; r < SGBLK; ++r) s += PB[(size_t)r*272 + e];
    red[e] = s;
  }
  __syncthreads();
  if (t < 16){
    float wv[16];
    #pragma unroll
    for (int ic = 0; ic < 16; ++ic) wv[ic] = w1[t*16+ic];
    float lin = 0.f;
    #pragma unroll
    for (int ic = 0; ic < 16; ++ic) lin += wv[ic]*red[256+ic];
    float quad = 0.f;
    for (int i = 0; i < 16; ++i){
      float ri = 0.f;
      #pragma unroll
      for (int j = 0; j < 16; ++j) ri += wv[j]*red[i*16+j];
      quad += wv[i]*ri;
    }
    float bb = b1[t];
    float S = lin + (float)NWN * bb;
    float Q = quad + 2.f*bb*lin + (float)NWN*bb*bb;
    float m = S * (1.f/NWN);
    float v = Q * (1.f/NWN) - m*m;
    float a = g1[t] * rsqrtf(v + EPSF);
    float d = be1[t] - m*a;
    a1sh[t] = a;
    F[320+t] = a*bb + d;
  }
  __syncthreads();
  F[64 + t] = a1sh[t >> 4] * w1[t];
}

// ---------------- k_red2: Gram -> layer2 BN -> folded w2f/b2f ----------------
__global__ __launch_bounds__(256) void k_red2(const float* PB, const float* w2, const float* b2,
                                              const float* g2, const float* be2, float* F){
  __shared__ float red[272];
  __shared__ float a2sh[64];
  int t = threadIdx.x;
  for (int e = t; e < 272; e += 256){
    float s = 0.f;
    for (int r = 0; r < SGBLK; ++r) s += PB[(size_t)r*272 + e];
    red[e] = s;
  }
  __syncthreads();
  if (t < 64){
    float wv[16];
    #pragma unroll
    for (int ic = 0; ic < 16; ++ic) wv[ic] = w2[t*16+ic];
    float lin = 0.f;
    #pragma unroll
    for (int ic = 0; ic < 16; ++ic) lin += wv[ic]*red[256+ic];
    float quad = 0.f;
    for (int i = 0; i < 16; ++i){
      float ri = 0.f;
      #pragma unroll
      for (int j = 0; j < 16; ++j) ri += wv[j]*red[i*16+j];
      quad += wv[i]*ri;
    }
    float bb = b2[t];
    float S = lin + (float)NWN * bb;
    float Q = quad + 2.f*bb*lin + (float)NWN*bb*bb;
    float m = S * (1.f/NWN);
    float v = Q * (1.f/NWN) - m*m;
    float a = g2[t] * rsqrtf(v + EPSF);
    float d = be2[t] - m*a;
    a2sh[t] = a;
    F[1360+t] = a*bb + d;
  }
  __syncthreads();
  for (int i = t; i < 1024; i += 256) F[336+i] = a2sh[i >> 4] * w2[i];
}

// ---------------- K5: one point per block — gather + WeightNet + MFMA (folded weights) ----------------
__global__ __launch_bounds__(256) void k_main(const float* lcg, const int* nbrg,
    const float* points, const float* xyz, const float* F,
    u16* npw){
  __shared__ u16   Gr[32*72];
  __shared__ u16   Wr[32*72];
  __shared__ float H0s[32][17];
  __shared__ float H1s[32][20];
  __shared__ float lcs[32][4];
  __shared__ int   nbr[32];
  __shared__ float w0c[48], b0c[16];
  __shared__ float w1c[16][17], b1c[16];
  __shared__ float w2c[64][17], b2c[64];
  int t = threadIdx.x;
  int point = blockIdx.x;
  int bb = point >> 10;
  if (t < 48) w0c[t] = F[t];
  if (t < 16){ b0c[t] = F[48+t]; b1c[t] = F[320+t]; }
  w1c[t>>4][t&15] = F[64+t];
  for (int i = t; i < 1024; i += 256) w2c[i>>4][i&15] = F[336+i];
  if (t < 64) b2c[t] = F[1360+t];
  if (t < 32) nbr[t] = nbrg[(size_t)point * 32 + t];
  if (t < 96){ int k = t / 3, c = t % 3; lcs[k][c] = lcg[(size_t)point * 96 + t]; }
  __syncthreads();   // (A)

  // gather grouped -> Gr bf16
  {
    int k = t >> 3, c8 = t & 7;
    int n = nbr[k];
    const float* prow = points + (size_t)(bb * NN + n) * 61;
    u16x8 g;
    if (c8 < 7){
      f32x4 lo = *(const f32x4u*)(prow + c8*8);
      f32x4 hi = *(const f32x4u*)(prow + c8*8 + 4);
      g[0]=f2b(lo.x); g[1]=f2b(lo.y); g[2]=f2b(lo.z); g[3]=f2b(lo.w);
      g[4]=f2b(hi.x); g[5]=f2b(hi.y); g[6]=f2b(hi.z); g[7]=f2b(hi.w);
    } else {
      const float* xr = xyz + (size_t)(bb * NN + n) * 3;
      f32x4 lo = *(const f32x4u*)(prow + 56);
      g[0]=f2b(lo.x); g[1]=f2b(lo.y); g[2]=f2b(lo.z); g[3]=f2b(lo.w);
      g[4]=f2b(prow[60]);
      g[5]=f2b(xr[0]); g[6]=f2b(xr[1]); g[7]=f2b(xr[2]);
    }
    *(u16x8*)&Gr[k*72 + c8*8] = g;
  }
  // H0
  #pragma unroll
  for (int jj = 0; jj < 2; ++jj){
    int l2 = t + jj * 256; int k = l2 >> 4, oc = l2 & 15;
    float y = w0c[oc*3]*lcs[k][0] + w0c[oc*3+1]*lcs[k][1] + w0c[oc*3+2]*lcs[k][2] + b0c[oc];
    H0s[k][oc] = fmaxf(0.f, y);
  }
  __syncthreads();   // (B)
  // H1
  #pragma unroll
  for (int jj = 0; jj < 2; ++jj){
    int l2 = t + jj * 256; int k = l2 >> 4, oc = l2 & 15;
    float y = b1c[oc];
    #pragma unroll
    for (int ic = 0; ic < 16; ++ic) y += w1c[oc][ic] * H0s[k][ic];
    H1s[k][oc] = fmaxf(0.f, y);
  }
  __syncthreads();   // (C)
  // W -> Wr
  {
    int o = t & 63, kb = (t >> 6) * 8;
    float wrow[16];
    #pragma unroll
    for (int ic = 0; ic < 16; ++ic) wrow[ic] = w2c[o][ic];
    float bb2 = b2c[o];
    #pragma unroll
    for (int j = 0; j < 8; ++j){
      const f32x4* hr = (const f32x4*)&H1s[kb + j][0];
      f32x4 h0v = hr[0], h1v = hr[1], h2v = hr[2], h3v = hr[3];
      float y = bb2;
      y += wrow[0]*h0v.x + wrow[1]*h0v.y + wrow[2]*h0v.z + wrow[3]*h0v.w;
      y += wrow[4]*h1v.x + wrow[5]*h1v.y + wrow[6]*h1v.z + wrow[7]*h1v.w;
      y += wrow[8]*h2v.x + wrow[9]*h2v.y + wrow[10]*h2v.z + wrow[11]*h2v.w;
      y += wrow[12]*h3v.x + wrow[13]*h3v.y + wrow[14]*h3v.z + wrow[15]*h3v.w;
      Wr[(kb + j)*72 + o] = f2b(fmaxf(0.f, y));
    }
  }
  __syncthreads();   // (D)
  // MFMA + store
  {
    int w = t >> 6, l = t & 63;
    int li = l & 15, lk = (l >> 4) * 8, lr = (l >> 4) * 4;
    s16x8 bfrag;
    #pragma unroll
    for (int j = 0; j < 8; ++j) bfrag[j] = (short)Wr[(lk + j)*72 + w*16 + li];
    #pragma unroll
    for (int it = 0; it < 4; ++it){
      s16x8 afrag;
      #pragma unroll
      for (int j = 0; j < 8; ++j) afrag[j] = (short)Gr[(lk + j)*72 + it*16 + li];
      f32x4 z = {0.f, 0.f, 0.f, 0.f};
      f32x4 d = __builtin_amdgcn_mfma_f32_16x16x32_bf16(afrag, bfrag, z, 0, 0, 0);
      #pragma unroll
      for (int r = 0; r < 4; ++r)
        npw[(size_t)point*4096 + (size_t)(it*16 + lr + r)*64 + w*16 + li] = f2b(d[r]);
    }
  }
}

// ---------------- k_statC: channel stats from npw (streaming, coalesced) ----------------
__global__ __launch_bounds__(256) void k_statC(const u16* npw, float* PC){
  int t = threadIdx.x;
  float s[16], q[16];
  #pragma unroll
  for (int j = 0; j < 16; ++j){ s[j] = 0.f; q[j] = 0.f; }
  size_t rowbase = (size_t)blockIdx.x * 64;
  for (int p = 0; p < 64; ++p){
    const u16* row = npw + (rowbase + p) * 4096 + t * 16;
    u16x8 a = *(const u16x8*)row;
    u16x8 b = *(const u16x8*)(row + 8);
    #pragma unroll
    for (int j = 0; j < 8; ++j){ float v = bf(a[j]); s[j]   += v; q[j]   += v*v; }
    #pragma unroll
    for (int j = 0; j < 8; ++j){ float v = bf(b[j]); s[8+j] += v; q[8+j] += v*v; }
  }
  float* dst = PC + (size_t)blockIdx.x * 8192 + t * 16;
  #pragma unroll
  for (int j = 0; j < 16; ++j){ dst[j] = s[j]; dst[4096 + j] = q[j]; }
}

// ---------------- k_finC ----------------
__global__ __launch_bounds__(256) void k_finC(const float* PC, const float* gc, const float* bc,
                                              float* AC, float* DC){
  int ch = blockIdx.x * 256 + threadIdx.x;
  float s = 0.f, q = 0.f;
  for (int r = 0; r < 256; ++r){
    s += PC[(size_t)r * 8192 + ch];
    q += PC[(size_t)r * 8192 + 4096 + ch];
  }
  float m = s * (1.f/16384.f);
  float v = q * (1.f/16384.f) - m*m;
  float a = gc[ch] * rsqrtf(v + EPSF);
  AC[ch] = a; DC[ch] = bc[ch] - m*a;
}

// ---------------- k_linear: MFMA GEMM + fused bn+relu on A + final-BN partials ----------------
__global__ __launch_bounds__(256) void k_linear(const u16* npw, const float* AC, const float* DC,
                                                const u16* lwbt, const float* lb, float* yw,
                                                float* PL){
  __shared__ u16 Al[32*72];
  __shared__ u16 Bl[64*72];
  __shared__ float cps[64], cpq[64];
  int t = threadIdx.x;
  int w = t >> 6, l = t & 63;
  int rowbase = blockIdx.x * 32;
  int mt = w & 1, np2 = w >> 1;
  f32x4 acc0 = {0.f,0.f,0.f,0.f}, acc1 = acc0;
  for (int kb = 0; kb < 4096; kb += 64){
    __syncthreads();
    {
      int r = t >> 3, c8 = t & 7;
      int kk = kb + c8*8;
      u16x8 u = *(const u16x8*)(npw + (size_t)(rowbase + r)*4096 + kk);
      f32x4 alo = *(const f32x4*)(AC + kk), ahi = *(const f32x4*)(AC + kk + 4);
      f32x4 dlo = *(const f32x4*)(DC + kk), dhi = *(const f32x4*)(DC + kk + 4);
      u16x8 o;
      o[0] = f2b(fmaxf(0.f, alo.x*bf(u[0]) + dlo.x));
      o[1] = f2b(fmaxf(0.f, alo.y*bf(u[1]) + dlo.y));
      o[2] = f2b(fmaxf(0.f, alo.z*bf(u[2]) + dlo.z));
      o[3] = f2b(fmaxf(0.f, alo.w*bf(u[3]) + dlo.w));
      o[4] = f2b(fmaxf(0.f, ahi.x*bf(u[4]) + dhi.x));
      o[5] = f2b(fmaxf(0.f, ahi.y*bf(u[5]) + dhi.y));
      o[6] = f2b(fmaxf(0.f, ahi.z*bf(u[6]) + dhi.z));
      o[7] = f2b(fmaxf(0.f, ahi.w*bf(u[7]) + dhi.w));
      *(u16x8*)&Al[r*72 + c8*8] = o;
    }
    #pragma unroll
    for (int jj = 0; jj < 2; ++jj){
      int n = (t >> 3) + jj*32, c8 = t & 7;
      u16x8 u = *(const u16x8*)(lwbt + (size_t)n*4096 + kb + c8*8);
      *(u16x8*)&Bl[n*72 + c8*8] = u;
    }
    __syncthreads();
    #pragma unroll
    for (int ks = 0; ks < 2; ++ks){
      s16x8 af  = *(const s16x8*)&Al[(mt*16 + (l & 15))*72 + ks*32 + (l >> 4)*8];
      s16x8 bf0 = *(const s16x8*)&Bl[((np2*2    )*16 + (l & 15))*72 + ks*32 + (l >> 4)*8];
      s16x8 bf1 = *(const s16x8*)&Bl[((np2*2 + 1)*16 + (l & 15))*72 + ks*32 + (l >> 4)*8];
      acc0 = __builtin_amdgcn_mfma_f32_16x16x32_bf16(af, bf0, acc0, 0, 0, 0);
      acc1 = __builtin_amdgcn_mfma_f32_16x16x32_bf16(af, bf1, acc1, 0, 0, 0);
    }
  }
  int col0 = np2*32 + (l & 15), col1 = col0 + 16;
  float lb0 = lb[col0], lb1 = lb[col1];
  float s0 = 0.f, q0 = 0.f, s1 = 0.f, q1 = 0.f;
  if (t < 64){ cps[t] = 0.f; cpq[t] = 0.f; }
  __syncthreads();
  #pragma unroll
  for (int r = 0; r < 4; ++r){
    int row = rowbase + mt*16 + (l >> 4)*4 + r;
    float y0 = acc0[r] + lb0;
    float y1 = acc1[r] + lb1;
    yw[(size_t)row*64 + col0] = y0;
    yw[(size_t)row*64 + col1] = y1;
    s0 += y0; q0 += y0*y0; s1 += y1; q1 += y1*y1;
  }
  atomicAdd(&cps[col0], s0); atomicAdd(&cpq[col0], q0);
  atomicAdd(&cps[col1], s1); atomicAdd(&cpq[col1], q1);
  __syncthreads();
  if (t < 64){
    PL[blockIdx.x*128 + t]      = cps[t];
    PL[blockIdx.x*128 + 64 + t] = cpq[t];
  }
}

// ---------------- k_redF ----------------
__global__ __launch_bounds__(128) void k_redF(const float* PL, float* SL){
  int t = threadIdx.x;
  float s = 0.f;
  for (int b = 0; b < 512; ++b) s += PL[b*128 + t];
  SL[t] = s;
}

// ---------------- k_final ----------------
__global__ __launch_bounds__(256) void k_final(const float* yw, const float* SL,
                                               const float* gl, const float* bl, float* out){
  int e = (blockIdx.x * 256 + threadIdx.x) * 4;
  int o = e & 63;
  f32x4 y = *(const f32x4*)(yw + e);
  f32x4 r;
  #pragma unroll
  for (int j = 0; j < 4; ++j){
    float m = SL[o+j] * (1.f/16384.f);
    float v = SL[64+o+j] * (1.f/16384.f) - m*m;
    float a = gl[o+j] * rsqrtf(v + EPSF);
    float d = bl[o+j] - m*a;
    r[j] = fmaxf(0.f, a*y[j] + d);
  }
  *(f32x4*)(out + 49152 + e) = r;
}

extern "C" void kernel_launch(void* const* d_in, const int* in_sizes, int n_in,
                              void* d_out, int out_size, void* d_ws, size_t ws_size,
                              hipStream_t stream){
  (void)in_sizes; (void)n_in; (void)out_size; (void)ws_size;
  const float* xyz    = (const float*)d_in[0];
  const float* points = (const float*)d_in[1];
  const float* lc     = (const float*)d_in[2];
  const int*   nbrl   = (const int*)d_in[3];
  const int*   didx   = (const int*)d_in[4];
  const float* w0 = (const float*)d_in[5];
  const float* b0 = (const float*)d_in[6];
  const float* g0 = (const float*)d_in[7];
  const float* be0= (const float*)d_in[8];
  const float* w1 = (const float*)d_in[9];
  const float* b1 = (const float*)d_in[10];
  const float* g1 = (const float*)d_in[11];
  const float* be1= (const float*)d_in[12];
  const float* w2 = (const float*)d_in[13];
  const float* b2 = (const float*)d_in[14];
  const float* g2 = (const float*)d_in[15];
  const float* be2= (const float*)d_in[16];
  const float* gc = (const float*)d_in[17];
  const float* bc = (const float*)d_in[18];
  const float* lw = (const float*)d_in[19];
  const float* lb = (const float*)d_in[20];
  const float* gl = (const float*)d_in[21];
  const float* bl = (const float*)d_in[22];
  float* out = (float*)d_out;
  char* ws = (char*)d_ws;

  float* F   = (float*)ws;           // 1536 @0 (1424 used)
  float* SL  = F + 1536;             // 128
  float* AC  = SL + 128;             // 4096
  float* DC  = AC + 4096;            // 4096
  float* PA  = DC + 4096;            // 32768
  float* PB1 = PA + 32768;           // 512*272 = 139264
  float* PB2 = PB1 + 139264;         // 139264
  float* PL  = PB2 + 139264;         // 65536  (end ~386688 floats < 4 MB)
  float* PC  = (float*)(ws + 4194304);                        // 8 MB
  u16*  npw  = (u16*)(ws + 4194304 + 8388608);                // 128 MB bf16
  float* yw  = (float*)(ws + 4194304 + 8388608 + 134217728);  // 4 MB f32
  u16*  lwbt = (u16*)(ws + 4194304 + 8388608 + 134217728 + 4194304); // 512 KB

  k_init  <<<128,   256, 0, stream>>>(xyz, didx, out, lw, lwbt);
  k_stat0 <<<512,   256, 0, stream>>>(lc, PA);
  k_red0  <<<1,     256, 0, stream>>>(PA, w0, b0, g0, be0, F);
  k_statG<false><<<SGBLK, 256, 0, stream>>>(lc, F, PB1);
  k_red1  <<<1,     256, 0, stream>>>(PB1, w1, b1, g1, be1, F);
  k_statG<true> <<<SGBLK, 256, 0, stream>>>(lc, F, PB2);
  k_red2  <<<1,     256, 0, stream>>>(PB2, w2, b2, g2, be2, F);
  k_main  <<<16384, 256, 0, stream>>>(lc, nbrl, points, xyz, F, npw);
  k_statC <<<256,   256, 0, stream>>>(npw, PC);
  k_finC  <<<16,    256, 0, stream>>>(PC, gc, bc, AC, DC);
  k_linear<<<512,   256, 0, stream>>>(npw, AC, DC, lwbt, lb, yw, PL);
  k_redF  <<<1,     128, 0, stream>>>(PL, SL);
  k_final <<<1024,  256, 0, stream>>>(yw, SL, gl, bl, out);
}